// Round 2
// baseline (147.735 us; speedup 1.0000x reference)
//
#include <hip/hip_runtime.h>
#include <hip/hip_bf16.h>
#include <stdint.h>

#define N_PTS   4096
#define M_CODES 4096
#define ZDIM    1024
// fp8 tiled layout: elem (r,k) at seg(rb)*16384 + kg*128 + r16*8 + ke  (BYTES)
//   rb=r>>4, r16=r&15, kg=k>>3, ke=k&7. Chunk (rb,kg) = 16 rows x 8 k = 128 B.
//   Seg = 16 rows x 1024 k x 1 B = 16 KB.

typedef __attribute__((ext_vector_type(4))) float f32x4;
typedef __attribute__((ext_vector_type(8))) int   i32x8;

__device__ __forceinline__ unsigned enc_f32(float f) {
    unsigned u = __float_as_uint(f);
    return (u & 0x80000000u) ? ~u : (u | 0x80000000u);
}
__device__ __forceinline__ float dec_f32(unsigned e) {
    unsigned u = (e & 0x80000000u) ? (e ^ 0x80000000u) : ~e;
    return __uint_as_float(u);
}

// ---------------------------------------------------------------------------
// prep: fp32 -> fp8 e4m3 (OCP) + tiled layout + row sum-of-squares (fp32,
// pre-quantization — error enters as 2(e.dz+z.de), sigma~2 << 35.5 threshold).
// One block = 16 rows. grid 512 (256 z + 256 e).
// ---------------------------------------------------------------------------
#define PREP_PITCH_B 1040   // bytes per LDS row: 1024 + 16 pad
__global__ __launch_bounds__(256) void prep_kernel(
    const float* __restrict__ z, const float* __restrict__ e,
    uint8_t* __restrict__ zb, uint8_t* __restrict__ eb,
    float* __restrict__ zsq, float* __restrict__ esq,
    unsigned* __restrict__ min_enc) {
    __shared__ uint8_t tile[16 * PREP_PITCH_B];   // ~16.6 KB
    __shared__ float redbuf[16 * 4];

    const int t = threadIdx.x;
    const int b = blockIdx.x;
    if (b < 16) min_enc[b * 256 + t] = 0xFFFFFFFFu;

    const bool is_z = b < 256;
    const int rb = b & 255;
    const float* src = (is_z ? z : e) + (size_t)rb * 16 * ZDIM;
    uint8_t* dst = (is_z ? zb : eb) + (size_t)rb * 16384;   // 16 KB seg
    const int w = t >> 6, lane = t & 63;

    // Phase 1: coalesced loads, fp32 row sums (R8-proven reduction),
    // pack 4 floats -> 4 fp8 into one dword in LDS.
    #pragma unroll
    for (int it = 0; it < 16; it++) {
        float4 v = reinterpret_cast<const float4*>(src + (size_t)it * ZDIM)[t];
        int pk = 0;
        pk = __builtin_amdgcn_cvt_pk_fp8_f32(v.x, v.y, pk, false);
        pk = __builtin_amdgcn_cvt_pk_fp8_f32(v.z, v.w, pk, true);
        *reinterpret_cast<int*>(&tile[it * PREP_PITCH_B + t * 4]) = pk;
        float s = v.x * v.x + v.y * v.y + v.z * v.z + v.w * v.w;
        #pragma unroll
        for (int off = 1; off < 64; off <<= 1) s += __shfl_xor(s, off, 64);
        if (lane == 0) redbuf[it * 4 + w] = s;
    }
    __syncthreads();

    // Phase 2: transpose-store to tiled global (chunk c -> dst + c*8, linear).
    #pragma unroll
    for (int it2 = 0; it2 < 8; it2++) {
        const int c = it2 * 256 + t;          // 0..2047
        const int kg = c >> 4, r16 = c & 15;
        const unsigned long long val = *reinterpret_cast<const unsigned long long*>(
            &tile[r16 * PREP_PITCH_B + kg * 8]);
        *reinterpret_cast<unsigned long long*>(&dst[(size_t)c * 8]) = val;
    }
    if (t < 16) {
        float sq = redbuf[t * 4] + redbuf[t * 4 + 1] +
                   redbuf[t * 4 + 2] + redbuf[t * 4 + 3];
        const int row = rb * 16 + t;
        if (is_z) zsq[row] = sq; else esq[row] = sq;
    }
}

// ---------------------------------------------------------------------------
// gemm_min (fp8, MX path, spill-free): single-barrier double-buffered A-DMA
// pipeline (K-stage=128, 8 stages/barriers), compute via
// mfma_scale_f32_16x16x128_f8f6f4 with unit e8m0 scales (0x7F = 2^0) — one
// MFMA per (am,an) per stage, MX rate ~2x the non-scaled fp8 rate, identical
// e4m3 math. R1 lesson (rule #20 family): NO union type-punning for the
// i32x8 operands — it defeated SROA and spilled every fragment to scratch
// (112 MB WRITE_SIZE). Fragments are assembled via int2 loads + constant-
// index vector inserts; B fragments are four NAMED i32x8 scalars.
// Fragment layout 16x16x128: lane l = row (l&15), k = (l>>4)*32 + j; in the
// tiled layout: 4x 8B at q*512 + p*128 + r16*8 (p=0..3). A via LDS
// (ds_read_b64 x4/frag), B direct global (dwordx2 x4/frag). VGPR: acc 64 +
// B 32 + A 8 + addr ~= 115 < 128 -> 4 blocks/CU holds. C/D layout is the
// 16x16 shape layout -> epilogue unchanged. 256 thr = 4 waves (2x2 of
// 64x64), grid (32,32).
// ---------------------------------------------------------------------------
__global__ __launch_bounds__(256, 4) void gemm_min_kernel(
    const uint8_t* __restrict__ zb, const uint8_t* __restrict__ eb,
    const float* __restrict__ zsq, unsigned* __restrict__ min_enc) {
    __shared__ __align__(16) uint8_t As[32768];  // 2 x 16 KB (8 segs x 2 KB)
    __shared__ float zsq_s[128];
    __shared__ float colmin[2][128];

    const int t = threadIdx.x;        // 0..255
    const int bx = blockIdx.x;        // code (col) block
    const int by = blockIdx.y;        // point (row) block
    const int lane = t & 63;
    const int w = t >> 6;             // 0..3
    const int wm = w >> 1, wn = w & 1;
    const int lrow = lane & 15;       // r16: output row-within-16 / frag row
    const int q = lane >> 4;          // 0..3: k-group within fragment

    if (t < 128) zsq_s[t] = zsq[by * 128 + t];

    f32x4 acc[4][4];
    #pragma unroll
    for (int i = 0; i < 4; i++)
        #pragma unroll
        for (int j = 0; j < 4; j++) acc[i][j] = (f32x4){0.f, 0.f, 0.f, 0.f};

    // A staging: per stage 16 KB (8 segs x 2 KB run). Instr j (0..3) = 4 KB:
    // waves {0,1} -> seg 2j, waves {2,3} -> seg 2j+1; inner = (t&127)*16.
    // LDS dest = buf + seg*2048 + (t&127)*16  (wave-uniform base + lane*16).
    const int seg_half = t >> 7;            // 0..1
    const int inner = (t & 127) * 16;       // byte offset in 2 KB run
    const size_t a_seg0 = (size_t)(by * 8) * 16384;

    // Per-lane fragment byte offset within one seg's 2 KB K-stage window:
    // lane l needs k = q*32 + p*8 + ke  ->  bytes at q*512 + p*128 + r16*8.
    const int frag_off = q * 512 + lrow * 8;
    const uint8_t* b_frag =
        eb + (size_t)(bx * 8 + wn * 4) * 16384 + frag_off;

#define DMA_STAGE(st_)                                                        \
    {                                                                         \
        const int buf_ = ((st_) & 1) * 16384;                                 \
        const int koff_ = (st_) * 2048;  /* byte offset within seg */         \
        _Pragma("unroll")                                                     \
        for (int j = 0; j < 4; j++) {                                         \
            const uint8_t* ga = zb + a_seg0 +                                 \
                (size_t)(j * 2 + seg_half) * 16384 + koff_ + inner;           \
            __builtin_amdgcn_global_load_lds(                                 \
                (const __attribute__((address_space(1))) void*)ga,            \
                (__attribute__((address_space(3))) void*)(As + buf_ +         \
                    (j * 2 + seg_half) * 2048 + inner), 16, 0, 0);            \
        }                                                                     \
    }

    // Assemble i32x8 fragment from 4x 8B loads (constant-index inserts only;
    // SROA-safe, no memory round trip).
#define LOAD_FRAG(dst_, base_)                                                \
    {                                                                         \
        const int2 d0_ = *(const int2*)((base_));                             \
        const int2 d1_ = *(const int2*)((base_) + 128);                       \
        const int2 d2_ = *(const int2*)((base_) + 256);                       \
        const int2 d3_ = *(const int2*)((base_) + 384);                       \
        dst_[0] = d0_.x; dst_[1] = d0_.y;                                     \
        dst_[2] = d1_.x; dst_[3] = d1_.y;                                     \
        dst_[4] = d2_.x; dst_[5] = d2_.y;                                     \
        dst_[6] = d3_.x; dst_[7] = d3_.y;                                     \
    }

#define MXMFMA(a_, b_, c_)                                                    \
    __builtin_amdgcn_mfma_scale_f32_16x16x128_f8f6f4(                         \
        (a_), (b_), (c_), 0, 0, 0, 0x7F7F7F7F, 0, 0x7F7F7F7F)

    DMA_STAGE(0);
    for (int st = 0; st < 8; st++) {
        __syncthreads();                 // drains DMA(st)
        if (st < 7) DMA_STAGE(st + 1);   // overlaps with compute(st)
        const int buf = (st & 1) * 16384;
        const int koff = st * 2048;

        // B fragments (K=128): named scalars, live across the am loop.
        i32x8 bf0, bf1, bf2, bf3;
        LOAD_FRAG(bf0, b_frag + (size_t)0 * 16384 + koff);
        LOAD_FRAG(bf1, b_frag + (size_t)1 * 16384 + koff);
        LOAD_FRAG(bf2, b_frag + (size_t)2 * 16384 + koff);
        LOAD_FRAG(bf3, b_frag + (size_t)3 * 16384 + koff);

        // Stream A fragments; 4 MX MFMAs each (unit scales = 1.0).
        #pragma unroll
        for (int am = 0; am < 4; am++) {
            i32x8 af;
            LOAD_FRAG(af, As + buf + (wm * 4 + am) * 2048 + frag_off);
            acc[am][0] = MXMFMA(af, bf0, acc[am][0]);
            acc[am][1] = MXMFMA(af, bf1, acc[am][1]);
            acc[am][2] = MXMFMA(af, bf2, acc[am][2]);
            acc[am][3] = MXMFMA(af, bf3, acc[am][3]);
        }
    }
#undef DMA_STAGE
#undef LOAD_FRAG
#undef MXMFMA

    __syncthreads();

    // Epilogue (proven; C/D layout shape-determined): row = q*4+r, col = lrow.
    #pragma unroll
    for (int an = 0; an < 4; an++) {
        float v = 3.4e38f;
        #pragma unroll
        for (int am = 0; am < 4; am++) {
            const int rbase = wm * 64 + am * 16 + q * 4;
            f32x4 c = acc[am][an];
            v = fminf(v, zsq_s[rbase + 0] - 2.f * c[0]);
            v = fminf(v, zsq_s[rbase + 1] - 2.f * c[1]);
            v = fminf(v, zsq_s[rbase + 2] - 2.f * c[2]);
            v = fminf(v, zsq_s[rbase + 3] - 2.f * c[3]);
        }
        v = fminf(v, __shfl_xor(v, 16, 64));
        v = fminf(v, __shfl_xor(v, 32, 64));
        if (q == 0) colmin[wm][wn * 64 + an * 16 + lrow] = v;
    }
    __syncthreads();
    if (t < 128) {
        const float m = fminf(colmin[0][t], colmin[1][t]);
        atomicMin(&min_enc[bx * 128 + t], enc_f32(m));
    }
}

// ---------------------------------------------------------------------------
// finalize: mean_j (dec(min_enc[j]) + esq[j]) -> single fp32 scalar.
// ---------------------------------------------------------------------------
__global__ __launch_bounds__(256) void finalize_kernel(
    const unsigned* __restrict__ min_enc, const float* __restrict__ esq,
    float* __restrict__ out) {
    const int t = threadIdx.x;
    float s = 0.f;
    #pragma unroll
    for (int i = 0; i < M_CODES / 256; i++) {
        const int j = i * 256 + t;
        s += dec_f32(min_enc[j]) + esq[j];
    }
    #pragma unroll
    for (int off = 1; off < 64; off <<= 1) s += __shfl_xor(s, off, 64);
    __shared__ float red[4];
    if ((t & 63) == 0) red[t >> 6] = s;
    __syncthreads();
    if (t == 0) out[0] = (red[0] + red[1] + red[2] + red[3]) * (1.f / M_CODES);
}

extern "C" void kernel_launch(void* const* d_in, const int* in_sizes, int n_in,
                              void* d_out, int out_size, void* d_ws, size_t ws_size,
                              hipStream_t stream) {
    (void)in_sizes; (void)n_in; (void)out_size; (void)ws_size;
    const float* z = (const float*)d_in[0];
    const float* e = (const float*)d_in[1];
    char* ws = (char*)d_ws;
    uint8_t* zb = (uint8_t*)ws;                                          // 4 MB
    uint8_t* eb = (uint8_t*)(ws + ((size_t)4 << 20));                    // 4 MB
    float* zsq = (float*)(ws + ((size_t)8 << 20));                       // 16 KB
    float* esq = (float*)(ws + ((size_t)8 << 20) + 16384);               // 16 KB
    unsigned* min_enc = (unsigned*)(ws + ((size_t)8 << 20) + 32768);     // 16 KB

    prep_kernel<<<dim3(512), dim3(256), 0, stream>>>(
        z, e, zb, eb, zsq, esq, min_enc);
    gemm_min_kernel<<<dim3(32, 32), dim3(256), 0, stream>>>(
        zb, eb, zsq, min_enc);
    finalize_kernel<<<dim3(1), dim3(256), 0, stream>>>(min_enc, esq, (float*)d_out);
}

// Round 3
// 116.209 us; speedup vs baseline: 1.2713x; 1.2713x over previous
//
#include <hip/hip_runtime.h>
#include <hip/hip_bf16.h>
#include <stdint.h>

#define N_PTS   4096
#define M_CODES 4096
#define ZDIM    1024
// fp8 tiled layout: elem (r,k) at seg(rb)*16384 + kg*128 + r16*8 + ke  (BYTES)
//   rb=r>>4, r16=r&15, kg=k>>3, ke=k&7. Chunk (rb,kg) = 16 rows x 8 k = 128 B.
//   Seg = 16 rows x 1024 k x 1 B = 16 KB.

typedef __attribute__((ext_vector_type(4))) float f32x4;
typedef __attribute__((ext_vector_type(8))) int   i32x8;

__device__ __forceinline__ unsigned enc_f32(float f) {
    unsigned u = __float_as_uint(f);
    return (u & 0x80000000u) ? ~u : (u | 0x80000000u);
}
__device__ __forceinline__ float dec_f32(unsigned e) {
    unsigned u = (e & 0x80000000u) ? (e ^ 0x80000000u) : ~e;
    return __uint_as_float(u);
}

// ---------------------------------------------------------------------------
// prep: fp32 -> fp8 e4m3 (OCP) + tiled layout + row sum-of-squares (fp32,
// pre-quantization — error enters as 2(e.dz+z.de), sigma~2 << 35.5 threshold).
// One block = 16 rows. grid 512 (256 z + 256 e).
// ---------------------------------------------------------------------------
#define PREP_PITCH_B 1040   // bytes per LDS row: 1024 + 16 pad
__global__ __launch_bounds__(256) void prep_kernel(
    const float* __restrict__ z, const float* __restrict__ e,
    uint8_t* __restrict__ zb, uint8_t* __restrict__ eb,
    float* __restrict__ zsq, float* __restrict__ esq,
    unsigned* __restrict__ min_enc) {
    __shared__ uint8_t tile[16 * PREP_PITCH_B];   // ~16.6 KB
    __shared__ float redbuf[16 * 4];

    const int t = threadIdx.x;
    const int b = blockIdx.x;
    if (b < 16) min_enc[b * 256 + t] = 0xFFFFFFFFu;

    const bool is_z = b < 256;
    const int rb = b & 255;
    const float* src = (is_z ? z : e) + (size_t)rb * 16 * ZDIM;
    uint8_t* dst = (is_z ? zb : eb) + (size_t)rb * 16384;   // 16 KB seg
    const int w = t >> 6, lane = t & 63;

    // Phase 1: coalesced loads, fp32 row sums (R8-proven reduction),
    // pack 4 floats -> 4 fp8 into one dword in LDS.
    #pragma unroll
    for (int it = 0; it < 16; it++) {
        float4 v = reinterpret_cast<const float4*>(src + (size_t)it * ZDIM)[t];
        int pk = 0;
        pk = __builtin_amdgcn_cvt_pk_fp8_f32(v.x, v.y, pk, false);
        pk = __builtin_amdgcn_cvt_pk_fp8_f32(v.z, v.w, pk, true);
        *reinterpret_cast<int*>(&tile[it * PREP_PITCH_B + t * 4]) = pk;
        float s = v.x * v.x + v.y * v.y + v.z * v.z + v.w * v.w;
        #pragma unroll
        for (int off = 1; off < 64; off <<= 1) s += __shfl_xor(s, off, 64);
        if (lane == 0) redbuf[it * 4 + w] = s;
    }
    __syncthreads();

    // Phase 2: transpose-store to tiled global (chunk c -> dst + c*8, linear).
    #pragma unroll
    for (int it2 = 0; it2 < 8; it2++) {
        const int c = it2 * 256 + t;          // 0..2047
        const int kg = c >> 4, r16 = c & 15;
        const unsigned long long val = *reinterpret_cast<const unsigned long long*>(
            &tile[r16 * PREP_PITCH_B + kg * 8]);
        *reinterpret_cast<unsigned long long*>(&dst[(size_t)c * 8]) = val;
    }
    if (t < 16) {
        float sq = redbuf[t * 4] + redbuf[t * 4 + 1] +
                   redbuf[t * 4 + 2] + redbuf[t * 4 + 3];
        const int row = rb * 16 + t;
        if (is_z) zsq[row] = sq; else esq[row] = sq;
    }
}

// ---------------------------------------------------------------------------
// gemm_min (fp8, MX path): single-barrier double-buffered A-DMA pipeline
// (K-stage=128, 8 stages/barriers), compute via
// mfma_scale_f32_16x16x128_f8f6f4 with unit e8m0 scales (0x7F = 2^0) — one
// MFMA per (am,an) per stage, MX rate ~2x non-scaled fp8, identical e4m3
// math.
// R2 lesson: __launch_bounds__(256,4) capped VGPRs at 128; MX operand regs
// (acc 64 + 4 live i32x8 B-frags 32 + A-frag 8 + addressing ~30) demand
// ~135-150 -> compiler spilled per-stage (115 MB scratch WRITE_SIZE, kernel
// HBM-bound on its own spills, MfmaUtil 9%). Fix: (256,3) -> VGPR cap ~170,
// no spill, 3 blocks/CU (102 KB LDS) — same occupancy regime as the proven
// m97-class GEMMs.
// Fragment layout 16x16x128: lane l = row (l&15), k = (l>>4)*32 + j; tiled:
// 4x 8B at q*512 + p*128 + r16*8 (p=0..3). A via LDS (ds_read_b64 x4/frag,
// p*128+am*2048 fold into imm offsets), B direct global (dwordx2 x4/frag).
// C/D layout is the 16x16 shape layout -> epilogue unchanged. 256 thr =
// 4 waves (2x2 of 64x64), grid (32,32).
// ---------------------------------------------------------------------------
__global__ __launch_bounds__(256, 3) void gemm_min_kernel(
    const uint8_t* __restrict__ zb, const uint8_t* __restrict__ eb,
    const float* __restrict__ zsq, unsigned* __restrict__ min_enc) {
    __shared__ __align__(16) uint8_t As[32768];  // 2 x 16 KB (8 segs x 2 KB)
    __shared__ float zsq_s[128];
    __shared__ float colmin[2][128];

    const int t = threadIdx.x;        // 0..255
    const int bx = blockIdx.x;        // code (col) block
    const int by = blockIdx.y;        // point (row) block
    const int lane = t & 63;
    const int w = t >> 6;             // 0..3
    const int wm = w >> 1, wn = w & 1;
    const int lrow = lane & 15;       // r16: output row-within-16 / frag row
    const int q = lane >> 4;          // 0..3: k-group within fragment

    if (t < 128) zsq_s[t] = zsq[by * 128 + t];

    f32x4 acc[4][4];
    #pragma unroll
    for (int i = 0; i < 4; i++)
        #pragma unroll
        for (int j = 0; j < 4; j++) acc[i][j] = (f32x4){0.f, 0.f, 0.f, 0.f};

    // A staging: per stage 16 KB (8 segs x 2 KB run). Instr j (0..3) = 4 KB:
    // waves {0,1} -> seg 2j, waves {2,3} -> seg 2j+1; inner = (t&127)*16.
    // LDS dest = buf + seg*2048 + (t&127)*16  (wave-uniform base + lane*16).
    const int seg_half = t >> 7;            // 0..1
    const int inner = (t & 127) * 16;       // byte offset in 2 KB run
    const size_t a_seg0 = (size_t)(by * 8) * 16384;

    // Per-lane fragment byte offset within one seg's 2 KB K-stage window:
    // lane l needs k = q*32 + p*8 + ke  ->  bytes at q*512 + p*128 + r16*8.
    const int frag_off = q * 512 + lrow * 8;
    const uint8_t* b_frag =
        eb + (size_t)(bx * 8 + wn * 4) * 16384 + frag_off;

#define DMA_STAGE(st_)                                                        \
    {                                                                         \
        const int buf_ = ((st_) & 1) * 16384;                                 \
        const int koff_ = (st_) * 2048;  /* byte offset within seg */         \
        _Pragma("unroll")                                                     \
        for (int j = 0; j < 4; j++) {                                         \
            const uint8_t* ga = zb + a_seg0 +                                 \
                (size_t)(j * 2 + seg_half) * 16384 + koff_ + inner;           \
            __builtin_amdgcn_global_load_lds(                                 \
                (const __attribute__((address_space(1))) void*)ga,            \
                (__attribute__((address_space(3))) void*)(As + buf_ +         \
                    (j * 2 + seg_half) * 2048 + inner), 16, 0, 0);            \
        }                                                                     \
    }

    // Assemble i32x8 fragment from 4x 8B loads (constant-index inserts only;
    // SROA-safe, no memory round trip).
#define LOAD_FRAG(dst_, base_)                                                \
    {                                                                         \
        const int2 d0_ = *(const int2*)((base_));                             \
        const int2 d1_ = *(const int2*)((base_) + 128);                       \
        const int2 d2_ = *(const int2*)((base_) + 256);                       \
        const int2 d3_ = *(const int2*)((base_) + 384);                       \
        dst_[0] = d0_.x; dst_[1] = d0_.y;                                     \
        dst_[2] = d1_.x; dst_[3] = d1_.y;                                     \
        dst_[4] = d2_.x; dst_[5] = d2_.y;                                     \
        dst_[6] = d3_.x; dst_[7] = d3_.y;                                     \
    }

#define MXMFMA(a_, b_, c_)                                                    \
    __builtin_amdgcn_mfma_scale_f32_16x16x128_f8f6f4(                         \
        (a_), (b_), (c_), 0, 0, 0, 0x7F7F7F7F, 0, 0x7F7F7F7F)

    DMA_STAGE(0);
    for (int st = 0; st < 8; st++) {
        __syncthreads();                 // drains DMA(st)
        if (st < 7) DMA_STAGE(st + 1);   // overlaps with compute(st)
        const int buf = (st & 1) * 16384;
        const int koff = st * 2048;

        // B fragments (K=128): named scalars, live across the am loop.
        i32x8 bf0, bf1, bf2, bf3;
        LOAD_FRAG(bf0, b_frag + (size_t)0 * 16384 + koff);
        LOAD_FRAG(bf1, b_frag + (size_t)1 * 16384 + koff);
        LOAD_FRAG(bf2, b_frag + (size_t)2 * 16384 + koff);
        LOAD_FRAG(bf3, b_frag + (size_t)3 * 16384 + koff);

        // Stream A fragments; 4 MX MFMAs each (unit scales = 1.0).
        #pragma unroll
        for (int am = 0; am < 4; am++) {
            i32x8 af;
            LOAD_FRAG(af, As + buf + (wm * 4 + am) * 2048 + frag_off);
            acc[am][0] = MXMFMA(af, bf0, acc[am][0]);
            acc[am][1] = MXMFMA(af, bf1, acc[am][1]);
            acc[am][2] = MXMFMA(af, bf2, acc[am][2]);
            acc[am][3] = MXMFMA(af, bf3, acc[am][3]);
        }
    }
#undef DMA_STAGE
#undef LOAD_FRAG
#undef MXMFMA

    __syncthreads();

    // Epilogue (proven; C/D layout shape-determined): row = q*4+r, col = lrow.
    #pragma unroll
    for (int an = 0; an < 4; an++) {
        float v = 3.4e38f;
        #pragma unroll
        for (int am = 0; am < 4; am++) {
            const int rbase = wm * 64 + am * 16 + q * 4;
            f32x4 c = acc[am][an];
            v = fminf(v, zsq_s[rbase + 0] - 2.f * c[0]);
            v = fminf(v, zsq_s[rbase + 1] - 2.f * c[1]);
            v = fminf(v, zsq_s[rbase + 2] - 2.f * c[2]);
            v = fminf(v, zsq_s[rbase + 3] - 2.f * c[3]);
        }
        v = fminf(v, __shfl_xor(v, 16, 64));
        v = fminf(v, __shfl_xor(v, 32, 64));
        if (q == 0) colmin[wm][wn * 64 + an * 16 + lrow] = v;
    }
    __syncthreads();
    if (t < 128) {
        const float m = fminf(colmin[0][t], colmin[1][t]);
        atomicMin(&min_enc[bx * 128 + t], enc_f32(m));
    }
}

// ---------------------------------------------------------------------------
// finalize: mean_j (dec(min_enc[j]) + esq[j]) -> single fp32 scalar.
// ---------------------------------------------------------------------------
__global__ __launch_bounds__(256) void finalize_kernel(
    const unsigned* __restrict__ min_enc, const float* __restrict__ esq,
    float* __restrict__ out) {
    const int t = threadIdx.x;
    float s = 0.f;
    #pragma unroll
    for (int i = 0; i < M_CODES / 256; i++) {
        const int j = i * 256 + t;
        s += dec_f32(min_enc[j]) + esq[j];
    }
    #pragma unroll
    for (int off = 1; off < 64; off <<= 1) s += __shfl_xor(s, off, 64);
    __shared__ float red[4];
    if ((t & 63) == 0) red[t >> 6] = s;
    __syncthreads();
    if (t == 0) out[0] = (red[0] + red[1] + red[2] + red[3]) * (1.f / M_CODES);
}

extern "C" void kernel_launch(void* const* d_in, const int* in_sizes, int n_in,
                              void* d_out, int out_size, void* d_ws, size_t ws_size,
                              hipStream_t stream) {
    (void)in_sizes; (void)n_in; (void)out_size; (void)ws_size;
    const float* z = (const float*)d_in[0];
    const float* e = (const float*)d_in[1];
    char* ws = (char*)d_ws;
    uint8_t* zb = (uint8_t*)ws;                                          // 4 MB
    uint8_t* eb = (uint8_t*)(ws + ((size_t)4 << 20));                    // 4 MB
    float* zsq = (float*)(ws + ((size_t)8 << 20));                       // 16 KB
    float* esq = (float*)(ws + ((size_t)8 << 20) + 16384);               // 16 KB
    unsigned* min_enc = (unsigned*)(ws + ((size_t)8 << 20) + 32768);     // 16 KB

    prep_kernel<<<dim3(512), dim3(256), 0, stream>>>(
        z, e, zb, eb, zsq, esq, min_enc);
    gemm_min_kernel<<<dim3(32, 32), dim3(256), 0, stream>>>(
        zb, eb, zsq, min_enc);
    finalize_kernel<<<dim3(1), dim3(256), 0, stream>>>(min_enc, esq, (float*)d_out);
}